// Round 1
// baseline (347.810 us; speedup 1.0000x reference)
//
#include <hip/hip_runtime.h>
#include <hip/hip_bf16.h>
#include <cstdint>

// Fused: ConvTranspose2d(128->256, k=4, s=2, p=1) + MaxPool2 + Hardtanh + mean + tanh
// B=64, Cin=128, Cout=256, H=W=64. Output [64,256,1,1] fp32 (16384 elems).
//
// ws layout: acc[16384] f32 @0 ; xT NHWC bf16 [64][64][64][128] @65536 (67108864 B);
//            wT bf16 [16][256][128] @67174400 (1048576 B). Total ~65 MB.

typedef __attribute__((ext_vector_type(8))) short short8;
typedef __attribute__((ext_vector_type(4))) float f32x4;

#define SWZ 1   // XOR bank-swizzle on 256B-row LDS tiles (bijective; perf-only)

__device__ __forceinline__ void async16(const void* g, void* l) {
  __builtin_amdgcn_global_load_lds(
      reinterpret_cast<const unsigned int __attribute__((address_space(1)))*>(
          reinterpret_cast<uintptr_t>(g)),
      reinterpret_cast<unsigned int __attribute__((address_space(3)))*>(
          reinterpret_cast<uintptr_t>(l)),
      16, 0, 0);
}

__device__ __forceinline__ unsigned short f2bf(float f) {
  union { float f; unsigned int u; } v; v.f = f;
  unsigned int u = v.u;
  return (unsigned short)((u + 0x7fffu + ((u >> 16) & 1u)) >> 16);
}

// ---------------- Pass A: x NCHW f32 -> NHWC bf16 ----------------
__global__ __launch_bounds__(256) void k_xpose(const float* __restrict__ x,
                                               unsigned short* __restrict__ xT) {
  __shared__ float tile[64][132];
  int bid = blockIdx.x;
  int b = bid >> 6, h = bid & 63;
  const float* src = x + (size_t)b * 524288 + h * 64;  // x[b][cin][h][w], cin stride 4096
  int w = threadIdx.x & 63, cg = threadIdx.x >> 6;
#pragma unroll
  for (int cc = 0; cc < 32; ++cc) {
    int cin = cc * 4 + cg;
    tile[w][cin] = src[(size_t)cin * 4096 + w];
  }
  __syncthreads();
  unsigned short* dst = xT + (size_t)(b * 64 + h) * 8192;  // row = 64 w * 128 cin
#pragma unroll
  for (int it = 0; it < 4; ++it) {
    int e = it * 2048 + threadIdx.x * 8;
    int ww = e >> 7, cin = e & 127;
    unsigned int pk[4];
#pragma unroll
    for (int j = 0; j < 4; ++j) {
      unsigned int lo = f2bf(tile[ww][cin + 2 * j]);
      unsigned int hi = f2bf(tile[ww][cin + 2 * j + 1]);
      pk[j] = lo | (hi << 16);
    }
    *reinterpret_cast<uint4*>(dst + e) = make_uint4(pk[0], pk[1], pk[2], pk[3]);
  }
}

// ---------------- Pass B: w [cin][cout][kh][kw] f32 -> wT [kh*4+kw][cout][cin] bf16 ----
__global__ __launch_bounds__(256) void k_wpack(const float* __restrict__ w,
                                               unsigned short* __restrict__ wT) {
  int o = blockIdx.x * 256 + threadIdx.x;  // 524288 total
  int cin = o & 127;
  int cout = (o >> 7) & 255;
  int khkw = o >> 15;
  int kh = khkw >> 2, kw = khkw & 3;
  float f = w[((size_t)cin * 256 + cout) * 16 + kh * 4 + kw];
  wT[o] = f2bf(f);
}

// ---------------- Main fused kernel ----------------
// Block: 256 thr (4 waves). Tile: 2 pooled rows (M=128 px) x 128 couts.
// LDS: x tile [4 rows][66 cols][128 cin] bf16 = 67584 B, then 2x 32768 B w-slice bufs.
#define XROW_B   16896    // 66*128*2
#define WBUF0_B  67584
#define WBUF_SZ  32768
#define LDS_TOTAL 133120

__global__ __launch_bounds__(256, 1) void k_main(
    const unsigned short* __restrict__ xT,
    const unsigned short* __restrict__ wT,
    const float* __restrict__ bias,
    float* __restrict__ acc) {
  extern __shared__ char smem[];
  const int bid = blockIdx.x;
  const int nt = bid & 1;           // cout tile: n0 = nt*128
  const int pr = (bid >> 1) & 31;   // pooled rows 2pr, 2pr+1
  const int b  = bid >> 6;
  const int n0 = nt * 128;
  const int tid = threadIdx.x;
  const int lane = tid & 63;
  const int wid = tid >> 6;
  const int wm = wid >> 1;   // which pooled row (0/1)
  const int wn = wid & 1;    // cout offset wn*64 inside tile
  const int l15 = lane & 15;
  const int l4  = lane >> 4;

  // ---- stage x tile: wave `wid` stages input row ir = 2pr-1+wid ----
  {
    const int r = wid;
    const int ir = 2 * pr - 1 + r;
    char* rowbase = smem + r * XROW_B;
    f32x4 z = {0.f, 0.f, 0.f, 0.f};
    if ((unsigned)ir < 64u) {
      const char* g0 = (const char*)xT + (size_t)(b * 64 + ir) * 16384;
#pragma unroll
      for (int it = 0; it < 16; ++it) {
        int c = 1 + it * 4 + l4;
#if SWZ
        int key = ((r * 66 + c) & 7) << 4;
#else
        int key = 0;
#endif
        const char* srcp = g0 + (c - 1) * 256 + ((l15 * 16) ^ key);
        async16(srcp, rowbase + 256 + it * 1024);
      }
      if (lane < 16)       *reinterpret_cast<f32x4*>(rowbase + lane * 16) = z;         // col 0
      else if (lane < 32)  *reinterpret_cast<f32x4*>(rowbase + 65 * 256 + (lane - 16) * 16) = z; // col 65
    } else {
#pragma unroll
      for (int it = 0; it < 17; ++it) {
        int off = it * 1024 + lane * 16;
        if (off < XROW_B) *reinterpret_cast<f32x4*>(rowbase + off) = z;
      }
    }
  }

  auto stage_w = [&](int khkw, int buf) {
    char* dst = smem + WBUF0_B + buf * WBUF_SZ + wid * 8192;
    const char* g0 = (const char*)wT + ((size_t)khkw * 256 + n0) * 256;
#pragma unroll
    for (int it = 0; it < 8; ++it) {
      int cl = wid * 32 + it * 4 + l4;
#if SWZ
      int key = (cl & 7) << 4;
#else
      int key = 0;
#endif
      async16(g0 + cl * 256 + ((l15 * 16) ^ key), dst + it * 1024);
    }
  };

  // tap tables: index [qh][th] (identical for w-dim with [qw][tw])
  const int KHt[2][2] = {{1, 3}, {2, 0}};
  const int DHt[2][2] = {{0, -1}, {0, 1}};

  stage_w(5, 0);  // (q=0,t=0): kh=1,kw=1 -> khkw=5
  __syncthreads();

  f32x4 accf[4][4], rm[4][4];
#pragma unroll
  for (int mi = 0; mi < 4; ++mi)
#pragma unroll
    for (int ni = 0; ni < 4; ++ni) accf[mi][ni] = (f32x4){0.f, 0.f, 0.f, 0.f};

  unsigned boff[4]; int bkey[4];
#pragma unroll
  for (int ni = 0; ni < 4; ++ni) {
    int cl = wn * 64 + ni * 16 + l15;
    boff[ni] = cl * 256 + l4 * 16;
#if SWZ
    bkey[ni] = (cl & 7) << 4;
#else
    bkey[ni] = 0;
#endif
  }

#pragma unroll
  for (int q = 0; q < 4; ++q) {
    const int qh = q >> 1, qw = q & 1;
#pragma unroll
    for (int t = 0; t < 4; ++t) {
      const int th = t >> 1, tw = t & 1;
      const int idx = q * 4 + t;
      if (idx < 15) {  // prefetch next weight slice into other buffer
        const int nidx = idx + 1;
        const int q2 = nidx >> 2, t2 = nidx & 3;
        const int kh2 = KHt[q2 >> 1][t2 >> 1];
        const int kw2 = KHt[q2 & 1][t2 & 1];
        stage_w(kh2 * 4 + kw2, nidx & 1);
      }
      const int ar = wm + 1 + DHt[qh][th];  // x tile row for this tap
      const int dw = DHt[qw][tw];           // col shift for this tap
      unsigned aoff[4]; int akey[4];
#pragma unroll
      for (int mi = 0; mi < 4; ++mi) {
        int c = 1 + mi * 16 + l15 + dw;
        int rowi = ar * 66 + c;
        aoff[mi] = rowi * 256 + l4 * 16;
#if SWZ
        akey[mi] = (rowi & 7) << 4;
#else
        akey[mi] = 0;
#endif
      }
      char* wb = smem + WBUF0_B + (idx & 1) * WBUF_SZ;
#pragma unroll
      for (int kk = 0; kk < 4; ++kk) {
        short8 a[4], bb[4];
#pragma unroll
        for (int mi = 0; mi < 4; ++mi)
          a[mi] = *reinterpret_cast<const short8*>(smem + ((aoff[mi] + kk * 64) ^ akey[mi]));
#pragma unroll
        for (int ni = 0; ni < 4; ++ni)
          bb[ni] = *reinterpret_cast<const short8*>(wb + ((boff[ni] + kk * 64) ^ bkey[ni]));
#pragma unroll
        for (int mi = 0; mi < 4; ++mi)
#pragma unroll
          for (int ni = 0; ni < 4; ++ni)
            accf[mi][ni] = __builtin_amdgcn_mfma_f32_16x16x32_bf16(a[mi], bb[ni], accf[mi][ni], 0, 0, 0);
      }
      if (t == 3) {  // parity finished: fold into running max, reset acc
#pragma unroll
        for (int mi = 0; mi < 4; ++mi)
#pragma unroll
          for (int ni = 0; ni < 4; ++ni) {
            if (q == 0) {
              rm[mi][ni] = accf[mi][ni];
            } else {
#pragma unroll
              for (int rr = 0; rr < 4; ++rr)
                rm[mi][ni][rr] = fmaxf(rm[mi][ni][rr], accf[mi][ni][rr]);
            }
            accf[mi][ni] = (f32x4){0.f, 0.f, 0.f, 0.f};
          }
      }
      __syncthreads();
    }
  }

  // ---- epilogue: +bias, clamp, sum over pixels, reduce, atomicAdd ----
#pragma unroll
  for (int ni = 0; ni < 4; ++ni) {
    const int cout = n0 + wn * 64 + ni * 16 + l15;
    const float bv = bias[cout];
    float s = 0.f;
#pragma unroll
    for (int mi = 0; mi < 4; ++mi)
#pragma unroll
      for (int rr = 0; rr < 4; ++rr) {
        float v = rm[mi][ni][rr] + bv;
        v = fminf(1.f, fmaxf(-1.f, v));
        s += v;
      }
    s += __shfl_xor(s, 16, 64);
    s += __shfl_xor(s, 32, 64);
    if (lane < 16) atomicAdd(&acc[b * 256 + cout], s);
  }
}

// ---------------- finalize ----------------
__global__ __launch_bounds__(256) void k_fin(const float* __restrict__ acc,
                                             float* __restrict__ out) {
  int i = blockIdx.x * 256 + threadIdx.x;
  out[i] = tanhf(acc[i] * (1.0f / 4096.0f));
}

extern "C" void kernel_launch(void* const* d_in, const int* in_sizes, int n_in,
                              void* d_out, int out_size, void* d_ws, size_t ws_size,
                              hipStream_t stream) {
  const float* x    = (const float*)d_in[0];
  const float* w    = (const float*)d_in[1];
  const float* bias = (const float*)d_in[2];
  float* out = (float*)d_out;
  char* ws = (char*)d_ws;

  float* acc          = (float*)ws;                       // 65536 B
  unsigned short* xT  = (unsigned short*)(ws + 65536);    // 67108864 B
  unsigned short* wT  = (unsigned short*)(ws + 65536 + 67108864);  // 1048576 B

  hipMemsetAsync(acc, 0, 65536, stream);
  k_xpose<<<4096, 256, 0, stream>>>(x, xT);
  k_wpack<<<2048, 256, 0, stream>>>(w, wT);

  hipFuncSetAttribute(reinterpret_cast<const void*>(k_main),
                      hipFuncAttributeMaxDynamicSharedMemorySize, LDS_TOTAL);
  k_main<<<4096, 256, LDS_TOTAL, stream>>>(xT, wT, bias, acc);
  k_fin<<<64, 256, 0, stream>>>(acc, out);
}